// Round 1
// baseline (2281.397 us; speedup 1.0000x reference)
//
#include <hip/hip_runtime.h>
#include <hip/hip_bf16.h>

#define N_ 8192
#define T_ 12
#define B_ 2
#define FIN_ 8
#define HID_ 16

typedef short s8v __attribute__((ext_vector_type(8)));
typedef float f4v __attribute__((ext_vector_type(4)));

__device__ __forceinline__ float sigmoidf_(float x){ return 1.f/(1.f + __expf(-x)); }

// ---------- prep: L fp32 -> bf16 ----------
__global__ __launch_bounds__(256) void conv_L_kernel(const float* __restrict__ L,
                                                     __hip_bfloat16* __restrict__ Lb){
  const long total = (long)N_*N_;
  long i = ((long)blockIdx.x*blockDim.x + threadIdx.x)*8;
  const long stride = (long)gridDim.x*blockDim.x*8;
  for (; i < total; i += stride){
    float4 a = *(const float4*)(L+i);
    float4 b = *(const float4*)(L+i+4);
    unsigned x0 = (unsigned)__bfloat16_as_ushort(__float2bfloat16(a.x)) |
                  ((unsigned)__bfloat16_as_ushort(__float2bfloat16(a.y))<<16);
    unsigned x1 = (unsigned)__bfloat16_as_ushort(__float2bfloat16(a.z)) |
                  ((unsigned)__bfloat16_as_ushort(__float2bfloat16(a.w))<<16);
    unsigned x2 = (unsigned)__bfloat16_as_ushort(__float2bfloat16(b.x)) |
                  ((unsigned)__bfloat16_as_ushort(__float2bfloat16(b.y))<<16);
    unsigned x3 = (unsigned)__bfloat16_as_ushort(__float2bfloat16(b.z)) |
                  ((unsigned)__bfloat16_as_ushort(__float2bfloat16(b.w))<<16);
    uint4 o; o.x=x0; o.y=x1; o.z=x2; o.w=x3;
    *(uint4*)(Lb+i) = o;
  }
}

// ---------- prep: pack X transposed bf16: XT[t][b*8+f][n] ----------
__global__ __launch_bounds__(256) void pack_x_kernel(const float* __restrict__ X,
                                                     __hip_bfloat16* __restrict__ XT){
  int t = blockIdx.y;
  int idx = blockIdx.x*256 + threadIdx.x;           // 16*8192
  int c2 = idx >> 13, m = idx & (N_-1);
  int b = c2 >> 3, f = c2 & 7;
  XT[((long)t*16 + c2)*N_ + m] =
      __float2bfloat16(X[(((long)(b*T_ + t))*N_ + m)*FIN_ + f]);
}

// ---------- prep: pack h0 transposed bf16: hT[b*16+j][n] ----------
__global__ __launch_bounds__(256) void pack_h0_kernel(const float* __restrict__ H,
                                                      __hip_bfloat16* __restrict__ hT){
  int idx = blockIdx.x*256 + threadIdx.x;           // 32*8192
  int cidx = idx >> 13, m = idx & (N_-1);
  int b = cidx >> 4, j = cidx & 15;
  hT[idx] = __float2bfloat16(H[((long)b*N_ + m)*HID_ + j]);
}

// ---------- main skinny GEMM: Ypart[s][c][n] = L[n][m-slice s] @ V[m][c] ----------
// A-frag: lane holds L[rt*16 + (lane&15)][k0 + (lane>>4)*8 + e]   (row-major, b128)
// B-frag: lane holds V[k][c0 + (lane&15)] from transposed storage Vt[c][k] (b128)
// D-frag: lane holds Y[c = c0+(lane&15)][n_out = rt*16 + (lane>>4)*4 + reg]
__global__ __launch_bounds__(256) void mm48_kernel(
    const __hip_bfloat16* __restrict__ Lbf,   // [8192][8192]
    const __hip_bfloat16* __restrict__ Bh,    // [32][8192]  (h-side cols, transposed)
    const __hip_bfloat16* __restrict__ Bx,    // [16][8192]  (x-side cols, transposed)
    float* __restrict__ Ypart)                // [4][48][8192]
{
  const int wave = threadIdx.x >> 6;
  const int lane = threadIdx.x & 63;
  const int lid = lane & 15, g = lane >> 4;
  const int rt = blockIdx.x;                  // [0,512): 16-row tile
  const int s  = wave;                        // [0,4): m-slice of 2048
  const long mbeg = (long)s*2048 + g*8;

  const __hip_bfloat16* Ap = Lbf + (long)(rt*16 + lid)*N_ + mbeg;
  const __hip_bfloat16* B0 = Bh  + (long)lid*N_       + mbeg;
  const __hip_bfloat16* B1 = Bh  + (long)(16+lid)*N_  + mbeg;
  const __hip_bfloat16* B2 = Bx  + (long)lid*N_       + mbeg;

  f4v acc0 = {0.f,0.f,0.f,0.f};
  f4v acc1 = {0.f,0.f,0.f,0.f};
  f4v acc2 = {0.f,0.f,0.f,0.f};

  #pragma unroll 4
  for (int kk = 0; kk < 64; ++kk){
    s8v a  = *(const s8v*)(const void*)(Ap);  Ap += 32;
    s8v b0 = *(const s8v*)(const void*)(B0);  B0 += 32;
    s8v b1 = *(const s8v*)(const void*)(B1);  B1 += 32;
    s8v b2 = *(const s8v*)(const void*)(B2);  B2 += 32;
    acc0 = __builtin_amdgcn_mfma_f32_16x16x32_bf16(a, b0, acc0, 0, 0, 0);
    acc1 = __builtin_amdgcn_mfma_f32_16x16x32_bf16(a, b1, acc1, 0, 0, 0);
    acc2 = __builtin_amdgcn_mfma_f32_16x16x32_bf16(a, b2, acc2, 0, 0, 0);
  }

  const long nbase = (long)rt*16 + g*4;
  {
    float4 v0; v0.x=acc0[0]; v0.y=acc0[1]; v0.z=acc0[2]; v0.w=acc0[3];
    *(float4*)(Ypart + ((long)s*48 + 0*16 + lid)*N_ + nbase) = v0;
    float4 v1; v1.x=acc1[0]; v1.y=acc1[1]; v1.z=acc1[2]; v1.w=acc1[3];
    *(float4*)(Ypart + ((long)s*48 + 1*16 + lid)*N_ + nbase) = v1;
    float4 v2; v2.x=acc2[0]; v2.y=acc2[1]; v2.z=acc2[2]; v2.w=acc2[3];
    *(float4*)(Ypart + ((long)s*48 + 2*16 + lid)*N_ + nbase) = v2;
  }
}

// ---------- reduce 4 partials; emit packed bf16 (pass1) + fp32 un-transposed ----------
__global__ __launch_bounds__(256) void reduce_kernel(const float* __restrict__ Yp,
    __hip_bfloat16* __restrict__ Yt, float* __restrict__ Fh, float* __restrict__ Fx,
    int writePacked)
{
  const int SZ = 48*N_;
  int idx = blockIdx.x*256 + threadIdx.x;           // [0, 48*8192)
  float s = Yp[idx] + Yp[idx+SZ] + Yp[idx+2*SZ] + Yp[idx+3*SZ];
  int c = idx >> 13, m = idx & (N_-1);
  if (writePacked) Yt[idx] = __float2bfloat16(s);
  if (c < 32) Fh[((long)((c>>4)*N_ + m))*HID_ + (c&15)] = s;
  else        Fx[((long)(((c-32)>>3)*N_ + m))*FIN_ + ((c-32)&7)] = s;
}

// ---------- per-timestep gate / LSTM pointwise ----------
__global__ __launch_bounds__(256) void gate_kernel(
    const float* __restrict__ X, const float* __restrict__ H0, const float* __restrict__ C0,
    const float* __restrict__ Wx, const float* __restrict__ Wh,
    const float* __restrict__ bx, const float* __restrict__ bh,
    const float* __restrict__ wc, const float* __restrict__ bg,
    const float* __restrict__ u_, const float* __restrict__ p_,
    const float* __restrict__ v_, const float* __restrict__ w_,
    float* __restrict__ out, float* __restrict__ hs, float* __restrict__ cs,
    __hip_bfloat16* __restrict__ hT, int t)
{
  int idx = blockIdx.x*256 + threadIdx.x;   // [0, 16384)
  int b = idx >> 13, n = idx & (N_-1);

  const float* xp = X + (((long)(b*T_ + t))*N_ + n)*FIN_;
  const float* hp = (t==0) ? (H0 + ((long)b*N_ + n)*HID_)
                           : (hs + (((long)(t-1)*B_ + b)*N_ + n)*HID_);
  const float* cp = (t==0) ? (C0 + ((long)b*N_ + n)*HID_)
                           : (cs + (((long)(t-1)*B_ + b)*N_ + n)*HID_);
  const float* up = u_ + ((long)b*N_ + n)*HID_;
  const float* pp = p_ + ((long)b*N_ + n)*FIN_;
  const float* vp = v_ + ((long)b*N_ + n)*HID_;
  const float* wp = w_ + ((long)b*N_ + n)*FIN_;

  float x[8], pq[8], wq[8], h[16], u[16], v[16], c[16];
  for (int f=0; f<8;  ++f){ x[f]=xp[f]; pq[f]=pp[f]; wq[f]=wp[f]; }
  for (int j=0; j<16; ++j){ h[j]=hp[j]; u[j]=up[j]; v[j]=vp[j]; c[j]=cp[j]; }

  const float* Wxt = Wx + (long)t*4*3*FIN_*HID_;
  const float* Wht = Wh + (long)t*4*3*HID_*HID_;
  const float* bxt = bx + t*4*HID_;
  const float* bht = bh + t*4*HID_;
  const float* bgt = bg + t*4*HID_;
  const float* wct = wc + t*3*HID_;

  float hn[16], cn[16];
  for (int hd=0; hd<16; ++hd){
    float pre0 = bxt[0*16+hd] + bht[0*16+hd] + bgt[0*16+hd];
    float pre1 = bxt[1*16+hd] + bht[1*16+hd] + bgt[1*16+hd];
    float pre2 = bxt[2*16+hd] + bht[2*16+hd] + bgt[2*16+hd];
    float pre3 = bxt[3*16+hd] + bht[3*16+hd] + bgt[3*16+hd];
    for (int f=0; f<8; ++f){
      float t0 = x[f], t1 = pq[f], t2 = 2.f*wq[f] - x[f];
      pre0 += t0*Wxt[((0*3+0)*8+f)*16+hd] + t1*Wxt[((0*3+1)*8+f)*16+hd] + t2*Wxt[((0*3+2)*8+f)*16+hd];
      pre1 += t0*Wxt[((1*3+0)*8+f)*16+hd] + t1*Wxt[((1*3+1)*8+f)*16+hd] + t2*Wxt[((1*3+2)*8+f)*16+hd];
      pre2 += t0*Wxt[((2*3+0)*8+f)*16+hd] + t1*Wxt[((2*3+1)*8+f)*16+hd] + t2*Wxt[((2*3+2)*8+f)*16+hd];
      pre3 += t0*Wxt[((3*3+0)*8+f)*16+hd] + t1*Wxt[((3*3+1)*8+f)*16+hd] + t2*Wxt[((3*3+2)*8+f)*16+hd];
    }
    for (int j=0; j<16; ++j){
      float t0 = h[j], t1 = u[j], t2 = 2.f*v[j] - h[j];
      pre0 += t0*Wht[((0*3+0)*16+j)*16+hd] + t1*Wht[((0*3+1)*16+j)*16+hd] + t2*Wht[((0*3+2)*16+j)*16+hd];
      pre1 += t0*Wht[((1*3+0)*16+j)*16+hd] + t1*Wht[((1*3+1)*16+j)*16+hd] + t2*Wht[((1*3+2)*16+j)*16+hd];
      pre2 += t0*Wht[((2*3+0)*16+j)*16+hd] + t1*Wht[((2*3+1)*16+j)*16+hd] + t2*Wht[((2*3+2)*16+j)*16+hd];
      pre3 += t0*Wht[((3*3+0)*16+j)*16+hd] + t1*Wht[((3*3+1)*16+j)*16+hd] + t2*Wht[((3*3+2)*16+j)*16+hd];
    }
    float cc = c[hd];
    float ig = sigmoidf_(pre0 + wct[0*16+hd]*cc);
    float fg = sigmoidf_(pre1 + wct[1*16+hd]*cc);
    float cnew = fg*cc + ig*tanhf(pre2);
    float og = sigmoidf_(pre3 + wct[2*16+hd]*cnew);
    cn[hd] = cnew;
    hn[hd] = og*tanhf(cnew);
  }

  float* hso = hs  + (((long)t*B_ + b)*N_ + n)*HID_;
  float* cso = cs  + (((long)t*B_ + b)*N_ + n)*HID_;
  float* oo  = out + (((long)b*T_ + t)*N_ + n)*HID_;
  for (int j=0; j<16; ++j){
    hso[j] = hn[j]; cso[j] = cn[j]; oo[j] = hn[j];
    hT[(long)(b*16 + j)*N_ + n] = __float2bfloat16(hn[j]);
  }
}

extern "C" void kernel_launch(void* const* d_in, const int* in_sizes, int n_in,
                              void* d_out, int out_size, void* d_ws, size_t ws_size,
                              hipStream_t stream)
{
  const float* X  = (const float*)d_in[0];
  const float* L  = (const float*)d_in[1];
  const float* H  = (const float*)d_in[2];
  const float* C  = (const float*)d_in[3];
  const float* Wx = (const float*)d_in[4];
  const float* Wh = (const float*)d_in[5];
  const float* bx = (const float*)d_in[6];
  const float* bh = (const float*)d_in[7];
  const float* wc = (const float*)d_in[8];
  const float* bg = (const float*)d_in[9];

  float* out = (float*)d_out;
  float* hs  = out + (long)B_*T_*N_*HID_;
  float* cs  = hs  + (long)T_*B_*N_*HID_;

  // workspace layout (bytes)
  const size_t NEEDED = 148111360;   // ~141.2 MB
  if (ws_size < NEEDED) return;      // graceful fail -> visible in absmax, no corruption
  char* ws = (char*)d_ws;
  __hip_bfloat16* Lbf = (__hip_bfloat16*)(ws);                   // 128 MiB  [8192][8192]
  __hip_bfloat16* XT  = (__hip_bfloat16*)(ws + 134217728);       // 3 MiB    [12][16][8192]
  __hip_bfloat16* hT  = (__hip_bfloat16*)(ws + 137363456);       // 512 KiB  [32][8192]
  __hip_bfloat16* y1t = (__hip_bfloat16*)(ws + 137887744);       // 768 KiB  [48][8192]
  float* Ypart = (float*)(ws + 138674176);                       // 6 MiB    [4][48][8192]
  float* u_ = (float*)(ws + 144965632);                          // 1 MiB    [2][8192][16]
  float* p_ = (float*)(ws + 146014208);                          // 512 KiB  [2][8192][8]
  float* v_ = (float*)(ws + 146538496);                          // 1 MiB
  float* w_ = (float*)(ws + 147587072);                          // 512 KiB

  conv_L_kernel <<<8192, 256, 0, stream>>>(L, Lbf);
  pack_x_kernel <<<dim3(512,12), 256, 0, stream>>>(X, XT);
  pack_h0_kernel<<<1024, 256, 0, stream>>>(H, hT);

  for (int t = 0; t < T_; ++t){
    // pass 1: (u|p) = L @ (h | x_t)
    mm48_kernel  <<<512, 256, 0, stream>>>(Lbf, hT, XT + (long)t*16*N_, Ypart);
    reduce_kernel<<<1536,256, 0, stream>>>(Ypart, y1t, u_, p_, 1);
    // pass 2: (v|w) = L @ (u | p)
    mm48_kernel  <<<512, 256, 0, stream>>>(Lbf, y1t, y1t + (long)32*N_, Ypart);
    reduce_kernel<<<1536,256, 0, stream>>>(Ypart, y1t, v_, w_, 0);
    // gates + state update + outputs (+ packed bf16 h for next step)
    gate_kernel  <<<64,  256, 0, stream>>>(X, H, C, Wx, Wh, bx, bh, wc, bg,
                                           u_, p_, v_, w_, out, hs, cs, hT, t);
  }
}

// Round 2
// 1460.633 us; speedup vs baseline: 1.5619x; 1.5619x over previous
//
#include <hip/hip_runtime.h>
#include <hip/hip_bf16.h>

#define N_ 8192
#define T_ 12
#define B_ 2
#define FIN_ 8
#define HID_ 16
#define CGSZ 131072   // one column-group (16 cols) frag block: 256 kb * 64 lanes * 8 elems

typedef short s8v __attribute__((ext_vector_type(8)));
typedef float f4v __attribute__((ext_vector_type(4)));

__device__ __forceinline__ float sigmoidf_(float x){ return 1.f/(1.f + __expf(-x)); }

// ---------------- prep: L fp32 -> bf16 fragment-major ----------------
// Lp[((rt*256 + kb)*64 + l)*8 + e] = bf16( L[rt*16 + (l&15)][kb*32 + (l>>4)*8 + e] )
// LDS transpose: reads coalesced float4 rows, writes coalesced uint4 frags.
__global__ __launch_bounds__(256) void build_Lp_kernel(const float* __restrict__ L,
                                                       __hip_bfloat16* __restrict__ Lp){
  __shared__ unsigned short tile[16][264];   // 256 cols + 8 pad (16B) per row
  const int cb = blockIdx.x;   // 0..31  (256-col chunk)
  const int rt = blockIdx.y;   // 0..511 (16-row tile)
  const int tid = threadIdx.x;
  #pragma unroll
  for (int i = 0; i < 4; ++i){
    int flat = i*256 + tid;            // 0..1023
    int r  = flat >> 6;                // 0..15
    int c4 = flat & 63;                // 0..63  (float4 index)
    float4 v = *(const float4*)(L + (long)(rt*16 + r)*N_ + cb*256 + c4*4);
    tile[r][c4*4+0] = __bfloat16_as_ushort(__float2bfloat16(v.x));
    tile[r][c4*4+1] = __bfloat16_as_ushort(__float2bfloat16(v.y));
    tile[r][c4*4+2] = __bfloat16_as_ushort(__float2bfloat16(v.z));
    tile[r][c4*4+3] = __bfloat16_as_ushort(__float2bfloat16(v.w));
  }
  __syncthreads();
  #pragma unroll
  for (int j = 0; j < 2; ++j){
    int flat = j*256 + tid;            // 0..511
    int kbl = flat >> 6;               // 0..7 local kb
    int l   = flat & 63;
    int lid = l & 15, g = l >> 4;
    uint4 frag = *(const uint4*)&tile[lid][kbl*32 + g*8];
    *(uint4*)(Lp + (((long)rt*256 + cb*8 + kbl)*64 + l)*8) = frag;
  }
}

// ---------------- prep: X -> bf16 frag-major per t ----------------
// XTf[t][(kb*64 + l)*8 + e] = bf16( X[b][t][n][f] ), c = b*8+f = (l&15), n = kb*32+(l>>4)*8+e
__global__ __launch_bounds__(256) void pack_x_kernel(const float* __restrict__ X,
                                                     __hip_bfloat16* __restrict__ XTf){
  const int t = blockIdx.y;
  int flat = blockIdx.x*256 + threadIdx.x;   // 0..16383
  int l = flat & 63, kb = flat >> 6;
  int lid = l & 15, g = l >> 4;
  int b = lid >> 3, f = lid & 7;
  int n0 = kb*32 + g*8;
  unsigned short u[8];
  #pragma unroll
  for (int e = 0; e < 8; ++e)
    u[e] = __bfloat16_as_ushort(__float2bfloat16(
        X[(((long)(b*T_ + t))*N_ + n0 + e)*FIN_ + f]));
  *(uint4*)(XTf + ((long)t*CGSZ + ((long)kb*64 + l)*8)) = *(uint4*)u;
}

// ---------------- prep: h0 -> bf16 frag-major ----------------
// hTf[cg=b][(kb*64+l)*8+e] = bf16( H[b][n][j] ), j = l&15
__global__ __launch_bounds__(256) void pack_h0_kernel(const float* __restrict__ H,
                                                      __hip_bfloat16* __restrict__ hTf){
  int flat = blockIdx.x*256 + threadIdx.x;   // 0..32767
  int l = flat & 63, kb = (flat >> 6) & 255, b = flat >> 14;
  int lid = l & 15, g = l >> 4;
  int n0 = kb*32 + g*8;
  unsigned short u[8];
  #pragma unroll
  for (int e = 0; e < 8; ++e)
    u[e] = __bfloat16_as_ushort(__float2bfloat16(
        H[((long)b*N_ + n0 + e)*HID_ + lid]));
  *(uint4*)(hTf + ((long)b*CGSZ + ((long)kb*64 + l)*8)) = *(uint4*)u;
}

// ---------------- fused skinny GEMM: Y[48][8192] = (L @ V) ----------------
// 8 waves, each a 1024-wide K slice; LDS reduce; epilogue writes bf16 frag (pass1)
// and un-transposed fp32 gate operands.
__global__ __launch_bounds__(512) void mm48_kernel(
    const __hip_bfloat16* __restrict__ Lp,
    const __hip_bfloat16* __restrict__ B0f,   // cols 0-15  (frag-major)
    const __hip_bfloat16* __restrict__ B1f,   // cols 16-31
    const __hip_bfloat16* __restrict__ B2f,   // cols 32-47
    __hip_bfloat16* __restrict__ y1f,         // [3][CGSZ] frag-major bf16 out (pass1)
    float* __restrict__ Fh,                   // [2][8192][16]
    float* __restrict__ Fx,                   // [2][8192][8]
    int writePacked)
{
  __shared__ float red[8][3][64][4];          // 24 KB
  const int tid = threadIdx.x;
  const int w = tid >> 6, lane = tid & 63;
  const int rt = blockIdx.x;                  // 16-row tile
  const int kb0 = w*32;                       // this wave's K slice (1024 elems)

  const s8v* Ap = (const s8v*)(const void*)Lp + ((long)rt*256 + kb0)*64 + lane;
  const s8v* P0 = (const s8v*)(const void*)B0f + (long)kb0*64 + lane;
  const s8v* P1 = (const s8v*)(const void*)B1f + (long)kb0*64 + lane;
  const s8v* P2 = (const s8v*)(const void*)B2f + (long)kb0*64 + lane;

  f4v acc0 = {0.f,0.f,0.f,0.f};
  f4v acc1 = {0.f,0.f,0.f,0.f};
  f4v acc2 = {0.f,0.f,0.f,0.f};

  #pragma unroll 4
  for (int kk = 0; kk < 32; ++kk){
    s8v a  = Ap[(long)kk*64];
    s8v b0 = P0[(long)kk*64];
    s8v b1 = P1[(long)kk*64];
    s8v b2 = P2[(long)kk*64];
    acc0 = __builtin_amdgcn_mfma_f32_16x16x32_bf16(a, b0, acc0, 0, 0, 0);
    acc1 = __builtin_amdgcn_mfma_f32_16x16x32_bf16(a, b1, acc1, 0, 0, 0);
    acc2 = __builtin_amdgcn_mfma_f32_16x16x32_bf16(a, b2, acc2, 0, 0, 0);
  }

  *(f4v*)&red[w][0][lane][0] = acc0;
  *(f4v*)&red[w][1][lane][0] = acc1;
  *(f4v*)&red[w][2][lane][0] = acc2;
  __syncthreads();

  for (int v = tid; v < 768; v += 512){
    int cg = v >> 8, rem = v & 255;
    int lid = rem & 15, r = rem >> 4;
    int g = r >> 2, j = r & 3;
    float s = 0.f;
    #pragma unroll
    for (int ww = 0; ww < 8; ++ww) s += red[ww][cg][g*16 + lid][j];
    int n = rt*16 + r;
    if (writePacked){
      long o = (((long)cg*256 + (n >> 5))*64 + ((n >> 3) & 3)*16 + lid)*8 + (n & 7);
      y1f[o] = __float2bfloat16(s);
    }
    if (cg < 2) Fh[((long)cg*N_ + n)*HID_ + lid] = s;
    else        Fx[((long)(lid >> 3)*N_ + n)*FIN_ + (lid & 7)] = s;
  }
}

// ---------------- per-timestep gate / LSTM pointwise ----------------
__global__ __launch_bounds__(256) void gate_kernel(
    const float* __restrict__ X, const float* __restrict__ H0, const float* __restrict__ C0,
    const float* __restrict__ Wx, const float* __restrict__ Wh,
    const float* __restrict__ bx, const float* __restrict__ bh,
    const float* __restrict__ wc, const float* __restrict__ bg,
    const float* __restrict__ u_, const float* __restrict__ p_,
    const float* __restrict__ v_, const float* __restrict__ w_,
    float* __restrict__ out, float* __restrict__ hs, float* __restrict__ cs,
    __hip_bfloat16* __restrict__ hTf, int t)
{
  int idx = blockIdx.x*256 + threadIdx.x;   // [0, 16384)
  int b = idx >> 13, n = idx & (N_-1);

  const float* xp = X + (((long)(b*T_ + t))*N_ + n)*FIN_;
  const float* hp = (t==0) ? (H0 + ((long)b*N_ + n)*HID_)
                           : (hs + (((long)(t-1)*B_ + b)*N_ + n)*HID_);
  const float* cp = (t==0) ? (C0 + ((long)b*N_ + n)*HID_)
                           : (cs + (((long)(t-1)*B_ + b)*N_ + n)*HID_);
  const float* up = u_ + ((long)b*N_ + n)*HID_;
  const float* pp = p_ + ((long)b*N_ + n)*FIN_;
  const float* vp = v_ + ((long)b*N_ + n)*HID_;
  const float* wp = w_ + ((long)b*N_ + n)*FIN_;

  float x[8], pq[8], wq[8], h[16], u[16], v[16], c[16];
  for (int f=0; f<8;  ++f){ x[f]=xp[f]; pq[f]=pp[f]; wq[f]=wp[f]; }
  for (int j=0; j<16; ++j){ h[j]=hp[j]; u[j]=up[j]; v[j]=vp[j]; c[j]=cp[j]; }

  const float* Wxt = Wx + (long)t*4*3*FIN_*HID_;
  const float* Wht = Wh + (long)t*4*3*HID_*HID_;
  const float* bxt = bx + t*4*HID_;
  const float* bht = bh + t*4*HID_;
  const float* bgt = bg + t*4*HID_;
  const float* wct = wc + t*3*HID_;

  float hn[16], cn[16];
  for (int hd=0; hd<16; ++hd){
    float pre0 = bxt[0*16+hd] + bht[0*16+hd] + bgt[0*16+hd];
    float pre1 = bxt[1*16+hd] + bht[1*16+hd] + bgt[1*16+hd];
    float pre2 = bxt[2*16+hd] + bht[2*16+hd] + bgt[2*16+hd];
    float pre3 = bxt[3*16+hd] + bht[3*16+hd] + bgt[3*16+hd];
    for (int f=0; f<8; ++f){
      float t0 = x[f], t1 = pq[f], t2 = 2.f*wq[f] - x[f];
      pre0 += t0*Wxt[((0*3+0)*8+f)*16+hd] + t1*Wxt[((0*3+1)*8+f)*16+hd] + t2*Wxt[((0*3+2)*8+f)*16+hd];
      pre1 += t0*Wxt[((1*3+0)*8+f)*16+hd] + t1*Wxt[((1*3+1)*8+f)*16+hd] + t2*Wxt[((1*3+2)*8+f)*16+hd];
      pre2 += t0*Wxt[((2*3+0)*8+f)*16+hd] + t1*Wxt[((2*3+1)*8+f)*16+hd] + t2*Wxt[((2*3+2)*8+f)*16+hd];
      pre3 += t0*Wxt[((3*3+0)*8+f)*16+hd] + t1*Wxt[((3*3+1)*8+f)*16+hd] + t2*Wxt[((3*3+2)*8+f)*16+hd];
    }
    for (int j=0; j<16; ++j){
      float t0 = h[j], t1 = u[j], t2 = 2.f*v[j] - h[j];
      pre0 += t0*Wht[((0*3+0)*16+j)*16+hd] + t1*Wht[((0*3+1)*16+j)*16+hd] + t2*Wht[((0*3+2)*16+j)*16+hd];
      pre1 += t0*Wht[((1*3+0)*16+j)*16+hd] + t1*Wht[((1*3+1)*16+j)*16+hd] + t2*Wht[((1*3+2)*16+j)*16+hd];
      pre2 += t0*Wht[((2*3+0)*16+j)*16+hd] + t1*Wht[((2*3+1)*16+j)*16+hd] + t2*Wht[((2*3+2)*16+j)*16+hd];
      pre3 += t0*Wht[((3*3+0)*16+j)*16+hd] + t1*Wht[((3*3+1)*16+j)*16+hd] + t2*Wht[((3*3+2)*16+j)*16+hd];
    }
    float cc = c[hd];
    float ig = sigmoidf_(pre0 + wct[0*16+hd]*cc);
    float fg = sigmoidf_(pre1 + wct[1*16+hd]*cc);
    float cnew = fg*cc + ig*tanhf(pre2);
    float og = sigmoidf_(pre3 + wct[2*16+hd]*cnew);
    cn[hd] = cnew;
    hn[hd] = og*tanhf(cnew);
  }

  float* hso = hs  + (((long)t*B_ + b)*N_ + n)*HID_;
  float* cso = cs  + (((long)t*B_ + b)*N_ + n)*HID_;
  float* oo  = out + (((long)b*T_ + t)*N_ + n)*HID_;
  const int kb = n >> 5, g = (n >> 3) & 3, e = n & 7;
  #pragma unroll
  for (int j=0; j<16; ++j){
    hso[j] = hn[j]; cso[j] = cn[j]; oo[j] = hn[j];
    hTf[(((long)b*256 + kb)*64 + g*16 + j)*8 + e] = __float2bfloat16(hn[j]);
  }
}

extern "C" void kernel_launch(void* const* d_in, const int* in_sizes, int n_in,
                              void* d_out, int out_size, void* d_ws, size_t ws_size,
                              hipStream_t stream)
{
  const float* X  = (const float*)d_in[0];
  const float* L  = (const float*)d_in[1];
  const float* H  = (const float*)d_in[2];
  const float* C  = (const float*)d_in[3];
  const float* Wx = (const float*)d_in[4];
  const float* Wh = (const float*)d_in[5];
  const float* bx = (const float*)d_in[6];
  const float* bh = (const float*)d_in[7];
  const float* wc = (const float*)d_in[8];
  const float* bg = (const float*)d_in[9];

  float* out = (float*)d_out;
  float* hs  = out + (long)B_*T_*N_*HID_;
  float* cs  = hs  + (long)T_*B_*N_*HID_;

  const size_t NEEDED = 141819904;
  if (ws_size < NEEDED) return;
  char* ws = (char*)d_ws;
  __hip_bfloat16* Lp  = (__hip_bfloat16*)(ws);                   // 128 MiB frag-major L
  __hip_bfloat16* XTf = (__hip_bfloat16*)(ws + 134217728);       // 3 MiB   [12][CGSZ]
  __hip_bfloat16* hTf = (__hip_bfloat16*)(ws + 137363456);       // 512 KiB [2][CGSZ]
  __hip_bfloat16* y1f = (__hip_bfloat16*)(ws + 137887744);       // 768 KiB [3][CGSZ]
  float* u_ = (float*)(ws + 138674176);                          // 1 MiB   [2][8192][16]
  float* p_ = (float*)(ws + 139722752);                          // 512 KiB [2][8192][8]
  float* v_ = (float*)(ws + 140247040);                          // 1 MiB
  float* w_ = (float*)(ws + 141295616);                          // 512 KiB

  build_Lp_kernel<<<dim3(32,512), 256, 0, stream>>>(L, Lp);
  pack_x_kernel  <<<dim3(64,12),  256, 0, stream>>>(X, XTf);
  pack_h0_kernel <<<128,          256, 0, stream>>>(H, hTf);

  for (int t = 0; t < T_; ++t){
    // pass 1: [u(32) | p(16)] = L @ [h | x_t]
    mm48_kernel<<<512, 512, 0, stream>>>(Lp, hTf, hTf + CGSZ, XTf + (long)t*CGSZ,
                                         y1f, u_, p_, 1);
    // pass 2: [v(32) | w(16)] = L @ [u | p]
    mm48_kernel<<<512, 512, 0, stream>>>(Lp, y1f, y1f + CGSZ, y1f + 2*CGSZ,
                                         y1f, v_, w_, 0);
    // gates + state update + outputs (+ frag-major bf16 h for next step)
    gate_kernel<<<64, 256, 0, stream>>>(X, H, C, Wx, Wh, bx, bh, wc, bg,
                                        u_, p_, v_, w_, out, hs, cs, hTf, t);
  }
}